// Round 6
// baseline (181.147 us; speedup 1.0000x reference)
//
#include <hip/hip_runtime.h>
#include <hip/hip_bf16.h>

#define GAMMA 0.9865f

typedef __attribute__((ext_vector_type(8))) short bf16x8;
typedef __attribute__((ext_vector_type(4))) float f32x4;

static constexpr int Bb  = 8;
static constexpr int Tt  = 2048;
static constexpr int DIN = 1024;
static constexpr int Dd  = 1024;
static constexpr int Mm  = Bb * Tt;      // 16384
static constexpr int CL  = 64;           // chunk length for scan
static constexpr int NC  = Tt / CL;      // 32 chunks
static constexpr int NT  = DIN / 32;     // 32 K-tiles of BK=32

__device__ __forceinline__ void gload16(const void* g, void* l) {
  __builtin_amdgcn_global_load_lds(
      (const __attribute__((address_space(1))) void*)g,
      (__attribute__((address_space(3))) void*)l, 16, 0, 0);
}

__device__ __forceinline__ void bar() {
  asm volatile("" ::: "memory");
  __builtin_amdgcn_s_barrier();
  asm volatile("" ::: "memory");
}

// ---- K1a: wsum[d] = sum_e Wk[d][e] --------------------------------------
__global__ void wsum_kernel(const float* __restrict__ Wk, float* __restrict__ wsum) {
  int row  = blockIdx.x * 4 + (threadIdx.x >> 6);
  int lane = threadIdx.x & 63;
  const float4* rp = (const float4*)(Wk + (size_t)row * DIN);
  float s = 0.f;
#pragma unroll
  for (int i = 0; i < 4; ++i) {
    float4 v = rp[lane + i * 64];
    s += v.x + v.y + v.z + v.w;
  }
  for (int off = 32; off; off >>= 1) s += __shfl_down(s, off);
  if (lane == 0) wsum[row] = s;
}

// ---- K1b: Wt[n][k] = bf16(W[k][n]) for Wq and Wv -------------------------
__global__ void wt_kernel(const float* __restrict__ Wq, const float* __restrict__ Wv,
                          __hip_bfloat16* __restrict__ Wt) {
  const float* W = blockIdx.z ? Wv : Wq;
  __hip_bfloat16* outp = Wt + (size_t)blockIdx.z * DIN * Dd;
  __shared__ float tile[32][33];
  int k0 = blockIdx.x * 32, n0 = blockIdx.y * 32;
  int tx = threadIdx.x, ty = threadIdx.y;  // (32,8)
#pragma unroll
  for (int i = 0; i < 4; ++i)
    tile[ty + i * 8][tx] = W[(size_t)(k0 + ty + i * 8) * Dd + n0 + tx];
  __syncthreads();
#pragma unroll
  for (int i = 0; i < 4; ++i)
    outp[(size_t)(n0 + ty + i * 8) * DIN + k0 + tx] =
        __float2bfloat16(tile[tx][ty + i * 8]);
}

// ---- K3: 256x256 GEMM, BK=32, A staged as fp32 (cast fused in-register) --
// LDS per buffer: A fp32 256x32 = 32KB  |  B bf16 256x32 = 16KB; x2 = 96KB.
// A swizzle (8 chunks/128B row): ch ^ (row&7)      -> 2-way (free)
// B swizzle (4 chunks/64B row):  ch ^ ((row>>1)&3) -> 2-way (free)
// Both applied on pre-swizzled global source (linear gload_lds dest, rule 21)
// and on the ds_read address.

__device__ __forceinline__ void stageA_half(const float* g, char* l, int tid) {
  // 128 rows x 32 fp32 = 1024 chunks of 16B (4 fp32); 2 loads/thread
#pragma unroll
  for (int j = 0; j < 2; ++j) {
    int c = tid + j * 512;
    int row = c >> 3, ch = c & 7;
    gload16(g + (size_t)row * DIN + ((ch ^ (row & 7)) << 2), l + c * 16);
  }
}

__device__ __forceinline__ void stageB(const __hip_bfloat16* g, char* l, int tid) {
  // 256 rows x 32 bf16 = 1024 chunks of 16B (8 bf16); 2 loads/thread
#pragma unroll
  for (int j = 0; j < 2; ++j) {
    int c = tid + j * 512;
    int row = c >> 2, ch = c & 3;
    gload16(g + (size_t)row * DIN + ((ch ^ ((row >> 1) & 3)) << 3), l + c * 16);
  }
}

__device__ __forceinline__ bf16x8 ldsA_frag(const char* base, int row, int fq) {
  float4 f0 = *(const float4*)(base + (((row << 3) + ((fq * 2)     ^ (row & 7))) << 4));
  float4 f1 = *(const float4*)(base + (((row << 3) + ((fq * 2 + 1) ^ (row & 7))) << 4));
  union { __hip_bfloat16 h[8]; bf16x8 v; } u;
  u.h[0] = __float2bfloat16(f0.x); u.h[1] = __float2bfloat16(f0.y);
  u.h[2] = __float2bfloat16(f0.z); u.h[3] = __float2bfloat16(f0.w);
  u.h[4] = __float2bfloat16(f1.x); u.h[5] = __float2bfloat16(f1.y);
  u.h[6] = __float2bfloat16(f1.z); u.h[7] = __float2bfloat16(f1.w);
  return u.v;
}

__device__ __forceinline__ bf16x8 ldsB_frag(const char* base, int row, int fq) {
  return *(const bf16x8*)(base + (((row << 2) + (fq ^ ((row >> 1) & 3))) << 4));
}

__global__ __launch_bounds__(512, 2) void gemm8_kernel(
    const float* __restrict__ Aq, const float* __restrict__ Av,
    const __hip_bfloat16* __restrict__ Wt,
    __hip_bfloat16* __restrict__ Qbf, __hip_bfloat16* __restrict__ Vbf) {
  extern __shared__ char lds[];  // [2][A 32KB | B 16KB] = 96KB

  // XCD-bijective swizzle: 512 blocks, 512 % 8 == 0
  int lin = blockIdx.x;
  int wg  = (lin & 7) * 64 + (lin >> 3);
  int z   = wg >> 8, rem = wg & 255;
  int by  = rem & 3, bx = rem >> 2;

  const float* Ab = z ? Av : Aq;
  const int m0 = bx * 256, n0 = by * 256;
  const float* Ag = Ab + (size_t)m0 * DIN;
  const __hip_bfloat16* Bg = Wt + ((size_t)z * Dd + n0) * DIN;
  __hip_bfloat16* Cc = z ? Vbf : Qbf;

  const int tid = threadIdx.x;
  const int wv = tid >> 6, lane = tid & 63;
  const int wm = (wv >> 2) * 128, wn = (wv & 3) * 64;
  const int fq = lane >> 4, fr = lane & 15;

  f32x4 acc[8][4] = {};

  // prologue: stage tiles 0 and 1
  stageA_half(Ag,                 lds,                 tid);
  stageA_half(Ag + 128 * DIN,     lds + 16384,         tid);
  stageB(Bg,                      lds + 32768,         tid);
  stageA_half(Ag + 32,            lds + 49152,         tid);
  stageA_half(Ag + 128 * DIN + 32, lds + 49152 + 16384, tid);
  stageB(Bg + 32,                 lds + 49152 + 32768, tid);
  asm volatile("s_waitcnt vmcnt(6)" ::: "memory");
  bar();

  for (int t = 0; t < NT; ++t) {
    char* buf = lds + (t & 1) * 49152;
    const char* At = buf;
    const char* Bt = buf + 32768;
    bf16x8 a[8], b[4];

    // read + cast all fragments for this K-tile
#pragma unroll
    for (int mi = 0; mi < 8; ++mi)
      a[mi] = ldsA_frag(At, wm + mi * 16 + fr, fq);
#pragma unroll
    for (int ni = 0; ni < 4; ++ni)
      b[ni] = ldsB_frag(Bt, wn + ni * 16 + fr, fq);

    asm volatile("s_waitcnt lgkmcnt(0)" ::: "memory");
    bar();  // all waves done reading buf -> safe to restage

    // phase 1: stage A(t+2)h0 + B(t+2); MFMA n=0,1
    if (t + 2 < NT) {
      stageA_half(Ag + (size_t)(t + 2) * 32, buf, tid);
      stageB(Bg + (size_t)(t + 2) * 32, buf + 32768, tid);
    }
    __builtin_amdgcn_s_setprio(1);
#pragma unroll
    for (int mi = 0; mi < 8; ++mi)
#pragma unroll
      for (int ni = 0; ni < 2; ++ni)
        acc[mi][ni] = __builtin_amdgcn_mfma_f32_16x16x32_bf16(a[mi], b[ni], acc[mi][ni], 0, 0, 0);
    __builtin_amdgcn_s_setprio(0);

    // phase 2: stage A(t+2)h1; MFMA n=2,3
    if (t + 2 < NT)
      stageA_half(Ag + 128 * DIN + (size_t)(t + 2) * 32, buf + 16384, tid);
    __builtin_amdgcn_s_setprio(1);
#pragma unroll
    for (int mi = 0; mi < 8; ++mi)
#pragma unroll
      for (int ni = 2; ni < 4; ++ni)
        acc[mi][ni] = __builtin_amdgcn_mfma_f32_16x16x32_bf16(a[mi], b[ni], acc[mi][ni], 0, 0, 0);
    __builtin_amdgcn_s_setprio(0);

    // counted vmcnt (T4): ensure tile t+1 (staged at t-1) has landed
    if (t + 1 < NT) {
      if (t + 2 < NT) asm volatile("s_waitcnt vmcnt(6)" ::: "memory");
      else            asm volatile("s_waitcnt vmcnt(0)" ::: "memory");
    }
    bar();
  }

  // epilogue: C/D layout col=lane&15, row=(lane>>4)*4+reg
#pragma unroll
  for (int mi = 0; mi < 8; ++mi) {
#pragma unroll
    for (int ni = 0; ni < 4; ++ni) {
      f32x4 v = acc[mi][ni];
      int row = m0 + wm + mi * 16 + fq * 4;
      int col = n0 + wn + ni * 16 + fr;
#pragma unroll
      for (int j = 0; j < 4; ++j)
        Cc[(size_t)(row + j) * Dd + col] = __float2bfloat16(v[j]);
    }
  }
}

// ---- K4: ksum[i] = dot(xk[i,:], wsum) fp32 ------------------------------
__global__ void ksum_kernel(const float* __restrict__ xk, const float* __restrict__ wsum,
                            float* __restrict__ ksum) {
  int row  = blockIdx.x * 4 + (threadIdx.x >> 6);
  int lane = threadIdx.x & 63;
  const float4* rp = (const float4*)(xk + (size_t)row * DIN);
  const float4* wp = (const float4*)wsum;
  float s = 0.f;
#pragma unroll
  for (int i = 0; i < 4; ++i) {
    float4 a = rp[lane + i * 64];
    float4 w = wp[lane + i * 64];
    s += a.x * w.x + a.y * w.y + a.z * w.z + a.w * w.w;
  }
  for (int off = 32; off; off >>= 1) s += __shfl_down(s, off);
  if (lane == 0) ksum[row] = s;
}

// ---- K5: per-chunk local scan end values E[b][c][d] ---------------------
__global__ void scanA_kernel(const __hip_bfloat16* __restrict__ Vbf,
                             const float* __restrict__ ksum,
                             float* __restrict__ E) {
  int b = blockIdx.x, c = blockIdx.y;
  int d = blockIdx.z * 256 + threadIdx.x;
  const __hip_bfloat16* Vp = Vbf + ((size_t)(b * Tt + c * CL) * Dd) + d;
  const float* kp = ksum + b * Tt + c * CL;
  float s = 0.f;
#pragma unroll 8
  for (int t = 0; t < CL; ++t) {
    float u = kp[t] * __bfloat162float(Vp[(size_t)t * Dd]);
    if (c == 0 && t == 0) u = 0.f;
    s = s * GAMMA + u;
  }
  E[((size_t)b * NC + c) * Dd + d] = s;
}

// ---- K6: compose carries across chunks ----------------------------------
__global__ void scanB_kernel(const float* __restrict__ E, float* __restrict__ carry,
                             float gCL) {
  int b = blockIdx.x;
  int d = blockIdx.y * 256 + threadIdx.x;
  float send = 0.f;
  for (int c = 0; c < NC; ++c) {
    size_t idx = ((size_t)b * NC + c) * Dd + d;
    float e = E[idx];
    carry[idx] = send;          // S at end of chunk c-1
    send = e + gCL * send;
  }
}

// ---- K7: final scan with carry, out = Q * S -----------------------------
__global__ void final_kernel(const __hip_bfloat16* __restrict__ Vbf,
                             const __hip_bfloat16* __restrict__ Qbf,
                             const float* __restrict__ ksum,
                             const float* __restrict__ carry,
                             float* __restrict__ outp) {
  int b = blockIdx.x, c = blockIdx.y;
  int d = blockIdx.z * 256 + threadIdx.x;
  size_t base = ((size_t)(b * Tt + c * CL) * Dd) + d;
  float s = carry[((size_t)b * NC + c) * Dd + d];
  const float* kp = ksum + b * Tt + c * CL;
#pragma unroll 4
  for (int t = 0; t < CL; ++t) {
    float u = kp[t] * __bfloat162float(Vbf[base + (size_t)t * Dd]);
    if (c == 0 && t == 0) u = 0.f;
    s = s * GAMMA + u;
    outp[base + (size_t)t * Dd] = __bfloat162float(Qbf[base + (size_t)t * Dd]) * s;
  }
}

extern "C" void kernel_launch(void* const* d_in, const int* in_sizes, int n_in,
                              void* d_out, int out_size, void* d_ws, size_t ws_size,
                              hipStream_t stream) {
  (void)in_sizes; (void)n_in; (void)out_size; (void)ws_size;
  const float* xq = (const float*)d_in[0];
  const float* xk = (const float*)d_in[1];
  const float* xv = (const float*)d_in[2];
  const float* Wq = (const float*)d_in[3];
  const float* Wk = (const float*)d_in[4];
  const float* Wv = (const float*)d_in[5];
  float* outp = (float*)d_out;

  char* ws = (char*)d_ws;
  size_t off = 0;
  auto alloc = [&](size_t bytes) {
    char* p = ws + off;
    off += (bytes + 255) & ~(size_t)255;
    return p;
  };
  __hip_bfloat16* Wt    = (__hip_bfloat16*)alloc((size_t)2 * DIN * Dd * 2);
  __hip_bfloat16* Qbf   = (__hip_bfloat16*)alloc((size_t)Mm * Dd * 2);
  __hip_bfloat16* Vbf   = (__hip_bfloat16*)alloc((size_t)Mm * Dd * 2);
  float* wsum  = (float*)alloc((size_t)DIN * 4);
  float* ksum  = (float*)alloc((size_t)Mm * 4);
  float* E     = (float*)alloc((size_t)Bb * NC * Dd * 4);
  float* carry = (float*)alloc((size_t)Bb * NC * Dd * 4);

  double g = 1.0;
  for (int i = 0; i < CL; ++i) g *= (double)GAMMA;
  float gCL = (float)g;

  (void)hipFuncSetAttribute((const void*)gemm8_kernel,
                            hipFuncAttributeMaxDynamicSharedMemorySize, 98304);

  wsum_kernel<<<DIN / 4, 256, 0, stream>>>(Wk, wsum);
  wt_kernel<<<dim3(DIN / 32, Dd / 32, 2), dim3(32, 8), 0, stream>>>(Wq, Wv, Wt);
  ksum_kernel<<<Mm / 4, 256, 0, stream>>>(xk, wsum, ksum);
  gemm8_kernel<<<512, 512, 98304, stream>>>(xq, xv, Wt, Qbf, Vbf);
  scanA_kernel<<<dim3(Bb, NC, Dd / 256), 256, 0, stream>>>(Vbf, ksum, E);
  scanB_kernel<<<dim3(Bb, Dd / 256), 256, 0, stream>>>(E, carry, gCL);
  final_kernel<<<dim3(Bb, NC, Dd / 256), 256, 0, stream>>>(Vbf, Qbf, ksum, carry, outp);
}

// Round 7
// 157.004 us; speedup vs baseline: 1.1538x; 1.1538x over previous
//
#include <hip/hip_runtime.h>
#include <hip/hip_bf16.h>

#define GAMMA 0.9865f

typedef __attribute__((ext_vector_type(8))) short bf16x8;
typedef __attribute__((ext_vector_type(4))) float f32x4;

static constexpr int Bb  = 8;
static constexpr int Tt  = 2048;
static constexpr int DIN = 1024;
static constexpr int Dd  = 1024;
static constexpr int Mm  = Bb * Tt;      // 16384
static constexpr int CL  = 64;           // chunk length for scan
static constexpr int NC  = Tt / CL;      // 32 chunks
static constexpr int NT  = DIN / 64;     // 16 K-tiles of BK=64

__device__ __forceinline__ void gload16(const void* g, void* l) {
  __builtin_amdgcn_global_load_lds(
      (const __attribute__((address_space(1))) void*)g,
      (__attribute__((address_space(3))) void*)l, 16, 0, 0);
}

__device__ __forceinline__ void bar() {
  asm volatile("" ::: "memory");
  __builtin_amdgcn_s_barrier();
  asm volatile("" ::: "memory");
}

// ---- K1a: wsum[d] = sum_e Wk[d][e] --------------------------------------
__global__ void wsum_kernel(const float* __restrict__ Wk, float* __restrict__ wsum) {
  int row  = blockIdx.x * 4 + (threadIdx.x >> 6);
  int lane = threadIdx.x & 63;
  const float4* rp = (const float4*)(Wk + (size_t)row * DIN);
  float s = 0.f;
#pragma unroll
  for (int i = 0; i < 4; ++i) {
    float4 v = rp[lane + i * 64];
    s += v.x + v.y + v.z + v.w;
  }
  for (int off = 32; off; off >>= 1) s += __shfl_down(s, off);
  if (lane == 0) wsum[row] = s;
}

// ---- K1b: Wt[n][k] = bf16(W[k][n]) for Wq and Wv -------------------------
__global__ void wt_kernel(const float* __restrict__ Wq, const float* __restrict__ Wv,
                          __hip_bfloat16* __restrict__ Wt) {
  const float* W = blockIdx.z ? Wv : Wq;
  __hip_bfloat16* outp = Wt + (size_t)blockIdx.z * DIN * Dd;
  __shared__ float tile[32][33];
  int k0 = blockIdx.x * 32, n0 = blockIdx.y * 32;
  int tx = threadIdx.x, ty = threadIdx.y;  // (32,8)
#pragma unroll
  for (int i = 0; i < 4; ++i)
    tile[ty + i * 8][tx] = W[(size_t)(k0 + ty + i * 8) * Dd + n0 + tx];
  __syncthreads();
#pragma unroll
  for (int i = 0; i < 4; ++i)
    outp[(size_t)(n0 + ty + i * 8) * DIN + k0 + tx] =
        __float2bfloat16(tile[tx][ty + i * 8]);
}

// ---- K2: cast fp32 -> bf16, 16B stores, 1 in-stream + 1 out-stream/wave --
__global__ __launch_bounds__(256) void cast_kernel(
    const float* __restrict__ xq, const float* __restrict__ xv,
    __hip_bfloat16* __restrict__ oq, __hip_bfloat16* __restrict__ ov) {
  const float* src = blockIdx.y ? xv : xq;
  __hip_bfloat16* dst = blockIdx.y ? ov : oq;
  size_t i = (size_t)blockIdx.x * 256 + threadIdx.x;  // 8-float group index
  const float4* p = (const float4*)src;
  float4 a = p[i * 2], b = p[i * 2 + 1];
  union { __hip_bfloat16 h[8]; bf16x8 v; } u;
  u.h[0] = __float2bfloat16(a.x); u.h[1] = __float2bfloat16(a.y);
  u.h[2] = __float2bfloat16(a.z); u.h[3] = __float2bfloat16(a.w);
  u.h[4] = __float2bfloat16(b.x); u.h[5] = __float2bfloat16(b.y);
  u.h[6] = __float2bfloat16(b.z); u.h[7] = __float2bfloat16(b.w);
  ((bf16x8*)dst)[i] = u.v;
}

// ---- K3: 256x256 8-phase bf16 MFMA GEMM (T2+T3+T4+T5) — R3 known-good ----
// LDS: 2 buffers x (A 32KB | B 32KB) = 128 KiB dynamic.
// Chunk swizzle (T2): slot = ch ^ (row&7) on pre-swizzled global source and
// ds_read address (rule #21: linear LDS dest for global_load_lds).

__device__ __forceinline__ void stage_half(const __hip_bfloat16* g, char* l, int tid) {
#pragma unroll
  for (int j = 0; j < 2; ++j) {
    int c = tid + j * 512;
    int row = c >> 3, ch = c & 7;
    gload16(g + (size_t)row * DIN + ((ch ^ (row & 7)) << 3), l + c * 16);
  }
}

__device__ __forceinline__ bf16x8 lds_frag(const char* base, int row, int kc) {
  return *(const bf16x8*)(base + (((row << 3) + (kc ^ (row & 7))) << 4));
}

#define MFMA_QUAD(MLO, NLO)                                                  \
  _Pragma("unroll") for (int mi = 0; mi < 4; ++mi)                           \
  _Pragma("unroll") for (int ni = 0; ni < 2; ++ni)                           \
  _Pragma("unroll") for (int ks = 0; ks < 2; ++ks)                           \
      acc[(MLO) + mi][(NLO) + ni] = __builtin_amdgcn_mfma_f32_16x16x32_bf16( \
          a[(MLO) + mi][ks], b[(NLO) + ni][ks], acc[(MLO) + mi][(NLO) + ni], 0, 0, 0);

__global__ __launch_bounds__(512, 2) void gemm8_kernel(
    const __hip_bfloat16* __restrict__ Aq, const __hip_bfloat16* __restrict__ Av,
    const __hip_bfloat16* __restrict__ Wt,
    __hip_bfloat16* __restrict__ Qbf, __hip_bfloat16* __restrict__ Vbf) {
  extern __shared__ char lds[];  // [2][A 32KB | B 32KB]

  // XCD-bijective swizzle: 512 blocks, 512 % 8 == 0
  int lin = blockIdx.x;
  int wg  = (lin & 7) * 64 + (lin >> 3);
  int z   = wg >> 8, rem = wg & 255;
  int by  = rem & 3, bx = rem >> 2;

  const __hip_bfloat16* Ab = z ? Av : Aq;
  const int m0 = bx * 256, n0 = by * 256;
  const __hip_bfloat16* Ag = Ab + (size_t)m0 * DIN;
  const __hip_bfloat16* Bg = Wt + ((size_t)z * Dd + n0) * DIN;
  __hip_bfloat16* Cc = z ? Vbf : Qbf;

  const int tid = threadIdx.x;
  const int wv = tid >> 6, lane = tid & 63;
  const int wm = (wv >> 2) * 128, wn = (wv & 3) * 64;
  const int fq = lane >> 4, fr = lane & 15;

  f32x4 acc[8][4] = {};

  // prologue: tile0 (A+B), tile1 (A only; its B staged during tile0 phases)
  stage_half(Ag,                  lds,                 tid);
  stage_half(Ag + 128 * DIN,      lds + 16384,         tid);
  stage_half(Bg,                  lds + 32768,         tid);
  stage_half(Bg + 128 * DIN,      lds + 49152,         tid);
  stage_half(Ag + 64,             lds + 65536,         tid);
  stage_half(Ag + 128 * DIN + 64, lds + 65536 + 16384, tid);
  asm volatile("s_waitcnt vmcnt(4)" ::: "memory");
  bar();

  for (int t = 0; t < NT; ++t) {
    char* buf  = lds + (t & 1) * 65536;
    char* bufN = lds + ((t + 1) & 1) * 65536;
    const char* At = buf;
    const char* Bt = buf + 32768;
    bf16x8 a[8][2], b[4][2];

    // ---- P0: read a[0..3], b[0..1]; stage B(t+1)h0
#pragma unroll
    for (int mi = 0; mi < 4; ++mi)
#pragma unroll
      for (int ks = 0; ks < 2; ++ks)
        a[mi][ks] = lds_frag(At, wm + mi * 16 + fr, ks * 4 + fq);
#pragma unroll
    for (int ni = 0; ni < 2; ++ni)
#pragma unroll
      for (int ks = 0; ks < 2; ++ks)
        b[ni][ks] = lds_frag(Bt, wn + ni * 16 + fr, ks * 4 + fq);
    if (t + 1 < NT) stage_half(Bg + (size_t)(t + 1) * 64, bufN + 32768, tid);
    bar();
    __builtin_amdgcn_s_setprio(1);
    MFMA_QUAD(0, 0);
    __builtin_amdgcn_s_setprio(0);
    bar();

    // ---- P1: read a[4..7]; stage B(t+1)h1
#pragma unroll
    for (int mi = 4; mi < 8; ++mi)
#pragma unroll
      for (int ks = 0; ks < 2; ++ks)
        a[mi][ks] = lds_frag(At, wm + mi * 16 + fr, ks * 4 + fq);
    if (t + 1 < NT)
      stage_half(Bg + 128 * DIN + (size_t)(t + 1) * 64, bufN + 49152, tid);
    bar();
    __builtin_amdgcn_s_setprio(1);
    MFMA_QUAD(4, 0);
    __builtin_amdgcn_s_setprio(0);
    bar();

    // ---- P2: read b[2..3]; stage A(t+2)h0 into buf (A dead after P1)
#pragma unroll
    for (int ni = 2; ni < 4; ++ni)
#pragma unroll
      for (int ks = 0; ks < 2; ++ks)
        b[ni][ks] = lds_frag(Bt, wn + ni * 16 + fr, ks * 4 + fq);
    if (t + 2 < NT) stage_half(Ag + (size_t)(t + 2) * 64, buf, tid);
    bar();
    __builtin_amdgcn_s_setprio(1);
    MFMA_QUAD(0, 2);
    __builtin_amdgcn_s_setprio(0);
    bar();

    // ---- P3: stage A(t+2)h1; counted vmcnt once per tile (T4)
    if (t + 2 < NT)
      stage_half(Ag + 128 * DIN + (size_t)(t + 2) * 64, buf + 16384, tid);
    if (t + 1 < NT) {
      if (t + 2 < NT) asm volatile("s_waitcnt vmcnt(4)" ::: "memory");
      else            asm volatile("s_waitcnt vmcnt(0)" ::: "memory");
    }
    bar();
    __builtin_amdgcn_s_setprio(1);
    MFMA_QUAD(4, 2);
    __builtin_amdgcn_s_setprio(0);
    bar();
  }

  // epilogue: C/D layout col=lane&15, row=(lane>>4)*4+reg
#pragma unroll
  for (int mi = 0; mi < 8; ++mi) {
#pragma unroll
    for (int ni = 0; ni < 4; ++ni) {
      f32x4 v = acc[mi][ni];
      int row = m0 + wm + mi * 16 + fq * 4;
      int col = n0 + wn + ni * 16 + fr;
#pragma unroll
      for (int j = 0; j < 4; ++j)
        Cc[(size_t)(row + j) * Dd + col] = __float2bfloat16(v[j]);
    }
  }
}

// ---- K4: ksum[i] = dot(xk[i,:], wsum) fp32 ------------------------------
__global__ void ksum_kernel(const float* __restrict__ xk, const float* __restrict__ wsum,
                            float* __restrict__ ksum) {
  int row  = blockIdx.x * 4 + (threadIdx.x >> 6);
  int lane = threadIdx.x & 63;
  const float4* rp = (const float4*)(xk + (size_t)row * DIN);
  const float4* wp = (const float4*)wsum;
  float s = 0.f;
#pragma unroll
  for (int i = 0; i < 4; ++i) {
    float4 a = rp[lane + i * 64];
    float4 w = wp[lane + i * 64];
    s += a.x * w.x + a.y * w.y + a.z * w.z + a.w * w.w;
  }
  for (int off = 32; off; off >>= 1) s += __shfl_down(s, off);
  if (lane == 0) ksum[row] = s;
}

// ---- K5: per-chunk local scan end values E[b][c][d] ---------------------
__global__ void scanA_kernel(const __hip_bfloat16* __restrict__ Vbf,
                             const float* __restrict__ ksum,
                             float* __restrict__ E) {
  int b = blockIdx.x, c = blockIdx.y;
  int d = blockIdx.z * 256 + threadIdx.x;
  const __hip_bfloat16* Vp = Vbf + ((size_t)(b * Tt + c * CL) * Dd) + d;
  const float* kp = ksum + b * Tt + c * CL;
  float s = 0.f;
#pragma unroll 8
  for (int t = 0; t < CL; ++t) {
    float u = kp[t] * __bfloat162float(Vp[(size_t)t * Dd]);
    if (c == 0 && t == 0) u = 0.f;
    s = s * GAMMA + u;
  }
  E[((size_t)b * NC + c) * Dd + d] = s;
}

// ---- K6: compose carries across chunks ----------------------------------
__global__ void scanB_kernel(const float* __restrict__ E, float* __restrict__ carry,
                             float gCL) {
  int b = blockIdx.x;
  int d = blockIdx.y * 256 + threadIdx.x;
  float send = 0.f;
  for (int c = 0; c < NC; ++c) {
    size_t idx = ((size_t)b * NC + c) * Dd + d;
    float e = E[idx];
    carry[idx] = send;          // S at end of chunk c-1
    send = e + gCL * send;
  }
}

// ---- K7: final scan with carry, out = Q * S -----------------------------
__global__ void final_kernel(const __hip_bfloat16* __restrict__ Vbf,
                             const __hip_bfloat16* __restrict__ Qbf,
                             const float* __restrict__ ksum,
                             const float* __restrict__ carry,
                             float* __restrict__ outp) {
  int b = blockIdx.x, c = blockIdx.y;
  int d = blockIdx.z * 256 + threadIdx.x;
  size_t base = ((size_t)(b * Tt + c * CL) * Dd) + d;
  float s = carry[((size_t)b * NC + c) * Dd + d];
  const float* kp = ksum + b * Tt + c * CL;
#pragma unroll 4
  for (int t = 0; t < CL; ++t) {
    float u = kp[t] * __bfloat162float(Vbf[base + (size_t)t * Dd]);
    if (c == 0 && t == 0) u = 0.f;
    s = s * GAMMA + u;
    outp[base + (size_t)t * Dd] = __bfloat162float(Qbf[base + (size_t)t * Dd]) * s;
  }
}

extern "C" void kernel_launch(void* const* d_in, const int* in_sizes, int n_in,
                              void* d_out, int out_size, void* d_ws, size_t ws_size,
                              hipStream_t stream) {
  (void)in_sizes; (void)n_in; (void)out_size; (void)ws_size;
  const float* xq = (const float*)d_in[0];
  const float* xk = (const float*)d_in[1];
  const float* xv = (const float*)d_in[2];
  const float* Wq = (const float*)d_in[3];
  const float* Wk = (const float*)d_in[4];
  const float* Wv = (const float*)d_in[5];
  float* outp = (float*)d_out;

  char* ws = (char*)d_ws;
  size_t off = 0;
  auto alloc = [&](size_t bytes) {
    char* p = ws + off;
    off += (bytes + 255) & ~(size_t)255;
    return p;
  };
  __hip_bfloat16* xq_bf = (__hip_bfloat16*)alloc((size_t)Mm * DIN * 2);
  __hip_bfloat16* xv_bf = (__hip_bfloat16*)alloc((size_t)Mm * DIN * 2);
  __hip_bfloat16* Wt    = (__hip_bfloat16*)alloc((size_t)2 * DIN * Dd * 2);
  __hip_bfloat16* Qbf   = (__hip_bfloat16*)alloc((size_t)Mm * Dd * 2);
  __hip_bfloat16* Vbf   = (__hip_bfloat16*)alloc((size_t)Mm * Dd * 2);
  float* wsum  = (float*)alloc((size_t)DIN * 4);
  float* ksum  = (float*)alloc((size_t)Mm * 4);
  float* E     = (float*)alloc((size_t)Bb * NC * Dd * 4);
  float* carry = (float*)alloc((size_t)Bb * NC * Dd * 4);

  double g = 1.0;
  for (int i = 0; i < CL; ++i) g *= (double)GAMMA;
  float gCL = (float)g;

  (void)hipFuncSetAttribute((const void*)gemm8_kernel,
                            hipFuncAttributeMaxDynamicSharedMemorySize, 131072);

  wsum_kernel<<<DIN / 4, 256, 0, stream>>>(Wk, wsum);
  wt_kernel<<<dim3(DIN / 32, Dd / 32, 2), dim3(32, 8), 0, stream>>>(Wq, Wv, Wt);
  cast_kernel<<<dim3(Mm * DIN / 8 / 256, 2), 256, 0, stream>>>(xq, xv, xq_bf, xv_bf);
  ksum_kernel<<<Mm / 4, 256, 0, stream>>>(xk, wsum, ksum);
  gemm8_kernel<<<512, 512, 131072, stream>>>(xq_bf, xv_bf, Wt, Qbf, Vbf);
  scanA_kernel<<<dim3(Bb, NC, Dd / 256), 256, 0, stream>>>(Vbf, ksum, E);
  scanB_kernel<<<dim3(Bb, Dd / 256), 256, 0, stream>>>(E, carry, gCL);
  final_kernel<<<dim3(Bb, NC, Dd / 256), 256, 0, stream>>>(Vbf, Qbf, ksum, carry, outp);
}